// Round 1
// baseline (150.860 us; speedup 1.0000x reference)
//
#include <hip/hip_runtime.h>
#include <math.h>

#define B_ 16
#define N_ 1024
#define F_ 2048
#define FREQS_PER_BLOCK 64
#define SLICES 4
#define NS (N_ / SLICES)  // 256 samples per slice

// Block = 256 threads = 64 freqs (lanes within wave) x 4 N-slices (waves).
// Each thread does two passes of NS=256 sincosf over its slice; partials
// are combined through LDS. fp32 op order mirrors the numpy/jax reference
// (naive pow/exp fap path intentionally preserved).
__global__ __launch_bounds__(256) void ls_power_kernel(
    const float* __restrict__ t,
    const float* __restrict__ y,
    const float* __restrict__ mask,
    const float* __restrict__ freqs,
    float* __restrict__ p_out)
{
    const int tid   = threadIdx.x;
    const int fi    = tid & 63;      // freq within block
    const int slice = tid >> 6;      // which quarter of N
    const int b     = blockIdx.y;
    const int f     = blockIdx.x * FREQS_PER_BLOCK + fi;

    const float freq  = freqs[f];
    const float omega = 6.28318530717958647692f * freq;  // fp32 2*pi*f (matches jax f32)

    const float* __restrict__ tb = t    + b * N_;
    const float* __restrict__ yb = y    + b * N_;
    const float* __restrict__ mb = mask + b * N_;

    __shared__ float red[SLICES][4][FREQS_PER_BLOCK];

    // ---- pass 1: s_sum = sum sin(2*w*t)*m, c_sum = sum cos(2*w*t)*m ----
    float s_sum = 0.0f, c_sum = 0.0f;
    const int n0 = slice * NS;
#pragma unroll 4
    for (int n = n0; n < n0 + NS; ++n) {
        float tn = tb[n];
        float mn = mb[n];
        float arg = 2.0f * omega * tn;   // 2*fl(w*t) == fl(2w*t) (exact x2)
        float s, c;
        sincosf(arg, &s, &c);
        s_sum += s * mn;
        c_sum += c * mn;
    }
    red[slice][0][fi] = s_sum;
    red[slice][1][fi] = c_sum;
    __syncthreads();
    // every slice-thread recomputes the same totals (identical order -> identical bits)
    float S = ((red[0][0][fi] + red[1][0][fi]) + red[2][0][fi]) + red[3][0][fi];
    float C = ((red[0][1][fi] + red[1][1][fi]) + red[2][1][fi]) + red[3][1][fi];
    float tau = atan2f(S, C) / (2.0f * omega);
    __syncthreads();   // before reusing `red`

    // ---- pass 2: projections onto cos/sin(w*(t - tau)) ----
    float yc = 0.0f, ys = 0.0f, cc = 0.0f, ss = 0.0f;
#pragma unroll 4
    for (int n = n0; n < n0 + NS; ++n) {
        float tn = tb[n];
        float mn = mb[n];
        float yn = yb[n];
        float arg = omega * (tn - tau);
        float s, c;
        sincosf(arg, &s, &c);
        c *= mn;                 // cos_term = cos(...) * mask
        s *= mn;                 // sin_term = sin(...) * mask
        yc += yn * c;
        ys += yn * s;
        cc += c * c;
        ss += s * s;
    }
    red[slice][0][fi] = yc;
    red[slice][1][fi] = ys;
    red[slice][2][fi] = cc;
    red[slice][3][fi] = ss;
    __syncthreads();

    if (slice == 0) {
        float YC = ((red[0][0][fi] + red[1][0][fi]) + red[2][0][fi]) + red[3][0][fi];
        float YS = ((red[0][1][fi] + red[1][1][fi]) + red[2][1][fi]) + red[3][1][fi];
        float CC = ((red[0][2][fi] + red[1][2][fi]) + red[2][2][fi]) + red[3][2][fi];
        float SS = ((red[0][3][fi] + red[1][3][fi]) + red[2][3][fi]) + red[3][3][fi];

        float p_cos = (YC * YC) / (CC + 1e-10f);
        float p_sin = (YS * YS) / (SS + 1e-10f);
        float p = 0.5f * (p_cos + p_sin);

        // fap = 1 - (1 - exp(-p))^M  -- naive fp32, matching the reference
        float fap = 1.0f - powf(1.0f - expf(-p), (float)F_);
        p = p * (1.0f / (fap + 1e-5f));

        p_out[b * F_ + f] = p;
    }
}

// One block per batch: trapezoid integral over F, then in-place normalize.
__global__ __launch_bounds__(256) void ls_norm_kernel(
    const float* __restrict__ freqs,
    float* __restrict__ p)   // d_out, in place
{
    const int b   = blockIdx.x;
    const int tid = threadIdx.x;
    float* __restrict__ pb = p + b * F_;

    float local = 0.0f;
    for (int j = tid; j < F_ - 1; j += 256) {
        float df = freqs[j + 1] - freqs[j];
        local += 0.5f * (pb[j] + pb[j + 1]) * df;
    }

    __shared__ float sred[256];
    sred[tid] = local;
    __syncthreads();
    for (int o = 128; o > 0; o >>= 1) {
        if (tid < o) sred[tid] += sred[tid + o];
        __syncthreads();
    }
    const float integral = sred[0] + 1e-10f;

#pragma unroll
    for (int k = 0; k < F_ / 256; ++k) {
        int j = tid + k * 256;
        pb[j] = pb[j] / integral;
    }
}

extern "C" void kernel_launch(void* const* d_in, const int* in_sizes, int n_in,
                              void* d_out, int out_size, void* d_ws, size_t ws_size,
                              hipStream_t stream) {
    const float* t     = (const float*)d_in[0];
    const float* y     = (const float*)d_in[1];
    const float* mask  = (const float*)d_in[2];
    const float* freqs = (const float*)d_in[3];
    float* out = (float*)d_out;

    dim3 grid1(F_ / FREQS_PER_BLOCK, B_);   // 32 x 16 = 512 blocks
    ls_power_kernel<<<grid1, 256, 0, stream>>>(t, y, mask, freqs, out);
    ls_norm_kernel<<<B_, 256, 0, stream>>>(freqs, out);
}

// Round 3
// 86.228 us; speedup vs baseline: 1.7495x; 1.7495x over previous
//
#include <hip/hip_runtime.h>
#include <math.h>

#define B_ 16
#define N_ 1024
#define F_ 2048
#define FPB 32            // freqs per block
#define SLICES 8          // N-slices per block
#define NS (N_ / SLICES)  // 128 samples per slice

// Angles are 2*pi*(2*f*t) and 2*pi*(f*(t-tau)); the hardware v_sin/v_cos take
// REVOLUTIONS, so the argument is just f*t -- no pi multiply. Dekker-split the
// product so the fractional revolution is accurate to ~1 ulp even at 1000 rev
// (better than the reference's own fp32 radian-argument rounding).
__global__ __launch_bounds__(256) void ls_power_kernel(
    const float* __restrict__ t,
    const float* __restrict__ y,
    const float* __restrict__ mask,
    const float* __restrict__ freqs,
    float* __restrict__ p_out)
{
    const int tid   = threadIdx.x;
    const int fi    = tid & (FPB - 1);
    const int slice = tid >> 5;          // 0..7
    const int b     = blockIdx.y;
    const int f     = blockIdx.x * FPB + fi;

    __shared__ __align__(16) float sh_t[N_];
    __shared__ __align__(16) float sh_y[N_];
    __shared__ __align__(16) float sh_m[N_];
    __shared__ float red[SLICES][4][FPB];

    // stage one batch's t/y/mask into LDS (256 threads x float4)
    {
        const float4* t4 = (const float4*)(t    + b * N_);
        const float4* y4 = (const float4*)(y    + b * N_);
        const float4* m4 = (const float4*)(mask + b * N_);
        ((float4*)sh_t)[tid] = t4[tid];
        ((float4*)sh_y)[tid] = y4[tid];
        ((float4*)sh_m)[tid] = m4[tid];
    }

    const float freq  = freqs[f];
    const float omega = 6.28318530717958647692f * freq;  // matches ref fl(2pi)*f
    const float f2    = 2.0f * freq;                     // exact x2

    __syncthreads();

    // ---- pass 1: S = sum sin(2wt)*m, C = sum cos(2wt)*m  (only feeds tau,
    // which enters p at second order -> fast trig is safe here) ----
    float s_sum = 0.f, c_sum = 0.f;
    const int n0 = slice * NS;
#pragma unroll 8
    for (int n = n0; n < n0 + NS; ++n) {
        float tn = sh_t[n], mn = sh_m[n];
        float ph = f2 * tn;                              // revolutions, hi
        float pe = __builtin_fmaf(f2, tn, -ph);          // exact residual
        float r  = __builtin_amdgcn_fractf(ph) + pe;     // frac(2*f*t), ~1ulp
        float s  = __builtin_amdgcn_sinf(r);             // v_sin_f32
        float c  = __builtin_amdgcn_cosf(r);             // v_cos_f32
        s_sum = __builtin_fmaf(s, mn, s_sum);
        c_sum = __builtin_fmaf(c, mn, c_sum);
    }
    red[slice][0][fi] = s_sum;
    red[slice][1][fi] = c_sum;
    __syncthreads();

    float S = 0.f, C = 0.f;
#pragma unroll
    for (int k = 0; k < SLICES; ++k) { S += red[k][0][fi]; C += red[k][1][fi]; }
    const float tau = atan2f(S, C) / (2.0f * omega);
    __syncthreads();   // before reusing `red`

    // ---- pass 2: projections onto cos/sin(w*(t - tau)) ----
    float yc = 0.f, ys = 0.f, cc = 0.f, ss = 0.f;
#pragma unroll 8
    for (int n = n0; n < n0 + NS; ++n) {
        float tn = sh_t[n], mn = sh_m[n], yn = sh_y[n];
        float d  = tn - tau;                             // matches ref (t - tau)
        float ph = freq * d;                             // revolutions
        float pe = __builtin_fmaf(freq, d, -ph);
        float r  = __builtin_amdgcn_fractf(ph) + pe;
        float s  = __builtin_amdgcn_sinf(r) * mn;
        float c  = __builtin_amdgcn_cosf(r) * mn;
        yc = __builtin_fmaf(yn, c, yc);
        ys = __builtin_fmaf(yn, s, ys);
        cc = __builtin_fmaf(c, c, cc);
        ss = __builtin_fmaf(s, s, ss);
    }
    red[slice][0][fi] = yc;
    red[slice][1][fi] = ys;
    red[slice][2][fi] = cc;
    red[slice][3][fi] = ss;
    __syncthreads();

    if (slice == 0) {
        float YC = 0.f, YS = 0.f, CC = 0.f, SS = 0.f;
#pragma unroll
        for (int k = 0; k < SLICES; ++k) {
            YC += red[k][0][fi];
            YS += red[k][1][fi];
            CC += red[k][2][fi];
            SS += red[k][3][fi];
        }
        float p_cos = (YC * YC) / (CC + 1e-10f);
        float p_sin = (YS * YS) / (SS + 1e-10f);
        float p = 0.5f * (p_cos + p_sin);

        // fap = 1 - (1 - exp(-p))^2048 -- keep the naive fp32 path (matches np)
        float fap = 1.0f - powf(1.0f - expf(-p), 2048.0f);
        p = p * (1.0f / (fap + 1e-5f));

        p_out[b * F_ + f] = p;
    }
}

// One block per batch: trapezoid integral over F, then in-place normalize.
__global__ __launch_bounds__(256) void ls_norm_kernel(
    const float* __restrict__ freqs,
    float* __restrict__ p)   // d_out, in place
{
    const int b   = blockIdx.x;
    const int tid = threadIdx.x;
    float* __restrict__ pb = p + b * F_;

    float local = 0.0f;
    for (int j = tid; j < F_ - 1; j += 256) {
        float df = freqs[j + 1] - freqs[j];
        local += 0.5f * (pb[j] + pb[j + 1]) * df;
    }

    __shared__ float sred[256];
    sred[tid] = local;
    __syncthreads();
    for (int o = 128; o > 0; o >>= 1) {
        if (tid < o) sred[tid] += sred[tid + o];
        __syncthreads();
    }
    const float integral = sred[0] + 1e-10f;

#pragma unroll
    for (int k = 0; k < F_ / 256; ++k) {
        int j = tid + k * 256;
        pb[j] = pb[j] / integral;
    }
}

extern "C" void kernel_launch(void* const* d_in, const int* in_sizes, int n_in,
                              void* d_out, int out_size, void* d_ws, size_t ws_size,
                              hipStream_t stream) {
    const float* t     = (const float*)d_in[0];
    const float* y     = (const float*)d_in[1];
    const float* mask  = (const float*)d_in[2];
    const float* freqs = (const float*)d_in[3];
    float* out = (float*)d_out;

    dim3 grid1(F_ / FPB, B_);   // 64 x 16 = 1024 blocks
    ls_power_kernel<<<grid1, 256, 0, stream>>>(t, y, mask, freqs, out);
    ls_norm_kernel<<<B_, 256, 0, stream>>>(freqs, out);
}

// Round 5
// 84.142 us; speedup vs baseline: 1.7929x; 1.0248x over previous
//
#include <hip/hip_runtime.h>
#include <math.h>

#define B_ 16
#define N_ 1024
#define F_ 2048
#define FPB 64            // freqs per block == lanes per wave (wave-uniform n!)
#define SLICES 16         // one N-slice per wave; 1024-thread blocks
#define NS (N_ / SLICES)  // 64 samples per slice
#define NC (NS / 4)       // 16 float4 chunks per slice

// Each wave owns 64 consecutive freqs (lane = freq) and one wave-UNIFORM
// slice of samples. Sample indices are forced uniform via readfirstlane so
// t/y/mask reads become scalar s_load_dwordx4 on the SMEM pipe (inputs are
// 12KB, L2-resident) -- no LDS staging, no per-lane address math.
//
// Angles are 2*pi*(2*f*t) and 2*pi*(f*(t-tau)); hardware v_sin/v_cos take
// REVOLUTIONS, so the argument is just f*t (no pi multiply). Pass 1 feeds
// only tau (second-order in p: tau merely orthogonalizes the basis) so the
// cheap fract(hi) is enough; pass 2 keeps the Dekker split (~1 ulp of a
// revolution even at 1000 revs, better than the reference's own fp32
// radian-argument rounding).
__global__ __launch_bounds__(1024) void ls_power_kernel(
    const float* __restrict__ t,
    const float* __restrict__ y,
    const float* __restrict__ mask,
    const float* __restrict__ freqs,
    float* __restrict__ p_out)
{
    const int tid   = threadIdx.x;
    const int fi    = tid & (FPB - 1);
    const int slice = tid >> 6;               // 0..15, wave index
    const int b     = blockIdx.y;
    const int f     = blockIdx.x * FPB + fi;

    const float freq  = freqs[f];
    const float omega = 6.28318530717958647692f * freq;  // matches ref fl(2pi)*f
    const float f2    = 2.0f * freq;                     // exact x2

    // wave-uniform float4 chunk base into the (b)-th row
    const int c0 = __builtin_amdgcn_readfirstlane(b * (N_ / 4) + slice * NC);
    const float4* __restrict__ t4 = (const float4*)t;
    const float4* __restrict__ y4 = (const float4*)y;
    const float4* __restrict__ m4 = (const float4*)mask;

    __shared__ float red[SLICES][4][FPB];

    // ---- pass 1: S = sum sin(2wt)*m, C = sum cos(2wt)*m ----
    float s_sum = 0.f, c_sum = 0.f;
#pragma unroll 4
    for (int ch = 0; ch < NC; ++ch) {
        float4 tv = t4[c0 + ch];
        float4 mv = m4[c0 + ch];
#pragma unroll
        for (int k = 0; k < 4; ++k) {
            float tn = (&tv.x)[k];
            float mn = (&mv.x)[k];
            float r  = __builtin_amdgcn_fractf(f2 * tn);   // frac revolutions
            float s  = __builtin_amdgcn_sinf(r);           // v_sin_f32
            float c  = __builtin_amdgcn_cosf(r);           // v_cos_f32
            s_sum = __builtin_fmaf(s, mn, s_sum);
            c_sum = __builtin_fmaf(c, mn, c_sum);
        }
    }
    red[slice][0][fi] = s_sum;
    red[slice][1][fi] = c_sum;
    __syncthreads();

    float S = 0.f, C = 0.f;
#pragma unroll
    for (int k = 0; k < SLICES; ++k) { S += red[k][0][fi]; C += red[k][1][fi]; }
    const float tau = atan2f(S, C) / (2.0f * omega);
    __syncthreads();   // before reusing `red`

    // ---- pass 2: projections onto cos/sin(w*(t - tau)) ----
    float yc = 0.f, ys = 0.f, cc = 0.f, ss = 0.f;
#pragma unroll 4
    for (int ch = 0; ch < NC; ++ch) {
        float4 tv = t4[c0 + ch];
        float4 yv = y4[c0 + ch];
        float4 mv = m4[c0 + ch];
#pragma unroll
        for (int k = 0; k < 4; ++k) {
            float tn = (&tv.x)[k];
            float yn = (&yv.x)[k];
            float mn = (&mv.x)[k];
            float d  = tn - tau;                           // matches ref (t - tau)
            float ph = freq * d;                           // revolutions, hi
            float pe = __builtin_fmaf(freq, d, -ph);       // exact residual
            float r  = __builtin_amdgcn_fractf(ph) + pe;   // ~1ulp fractional rev
            float s  = __builtin_amdgcn_sinf(r) * mn;
            float c  = __builtin_amdgcn_cosf(r) * mn;
            yc = __builtin_fmaf(yn, c, yc);
            ys = __builtin_fmaf(yn, s, ys);
            cc = __builtin_fmaf(c, c, cc);
            ss = __builtin_fmaf(s, s, ss);
        }
    }
    red[slice][0][fi] = yc;
    red[slice][1][fi] = ys;
    red[slice][2][fi] = cc;
    red[slice][3][fi] = ss;
    __syncthreads();

    if (slice == 0) {
        float YC = 0.f, YS = 0.f, CC = 0.f, SS = 0.f;
#pragma unroll
        for (int k = 0; k < SLICES; ++k) {
            YC += red[k][0][fi];
            YS += red[k][1][fi];
            CC += red[k][2][fi];
            SS += red[k][3][fi];
        }
        float p_cos = (YC * YC) / (CC + 1e-10f);
        float p_sin = (YS * YS) / (SS + 1e-10f);
        float p = 0.5f * (p_cos + p_sin);

        // fap = 1 - (1 - exp(-p))^2048 -- keep the naive fp32 path (matches np)
        float fap = 1.0f - powf(1.0f - expf(-p), 2048.0f);
        p = p * (1.0f / (fap + 1e-5f));

        p_out[b * F_ + f] = p;
    }
}

// One block per batch: trapezoid integral over F, then in-place normalize.
__global__ __launch_bounds__(256) void ls_norm_kernel(
    const float* __restrict__ freqs,
    float* __restrict__ p)   // d_out, in place
{
    const int b   = blockIdx.x;
    const int tid = threadIdx.x;
    float* __restrict__ pb = p + b * F_;

    float local = 0.0f;
    for (int j = tid; j < F_ - 1; j += 256) {
        float df = freqs[j + 1] - freqs[j];
        local += 0.5f * (pb[j] + pb[j + 1]) * df;
    }

    __shared__ float sred[256];
    sred[tid] = local;
    __syncthreads();
    for (int o = 128; o > 0; o >>= 1) {
        if (tid < o) sred[tid] += sred[tid + o];
        __syncthreads();
    }
    const float integral = sred[0] + 1e-10f;

#pragma unroll
    for (int k = 0; k < F_ / 256; ++k) {
        int j = tid + k * 256;
        pb[j] = pb[j] / integral;
    }
}

extern "C" void kernel_launch(void* const* d_in, const int* in_sizes, int n_in,
                              void* d_out, int out_size, void* d_ws, size_t ws_size,
                              hipStream_t stream) {
    const float* t     = (const float*)d_in[0];
    const float* y     = (const float*)d_in[1];
    const float* mask  = (const float*)d_in[2];
    const float* freqs = (const float*)d_in[3];
    float* out = (float*)d_out;

    dim3 grid1(F_ / FPB, B_);   // 32 x 16 = 512 blocks x 1024 threads
    ls_power_kernel<<<grid1, 1024, 0, stream>>>(t, y, mask, freqs, out);
    ls_norm_kernel<<<B_, 256, 0, stream>>>(freqs, out);
}

// Round 6
// 82.472 us; speedup vs baseline: 1.8292x; 1.0203x over previous
//
#include <hip/hip_runtime.h>
#include <math.h>

#define B_ 16
#define N_ 1024
#define F_ 2048
#define FPB 64            // freqs per block == lanes per wave
#define SLICES 16         // one N-slice per wave; 1024-thread blocks
#define NS (N_ / SLICES)  // 64 samples per slice
#define NC (NS / 4)       // 16 float4 chunks per slice

// Single-pass Lomb-Scargle (Press & Rybicki form). Per sample we compute
// s0=sin(wt), c0=cos(wt) ONCE (hardware v_sin/v_cos in revolutions, Dekker
// split for ~1ulp fractional revolution) and accumulate:
//   S  = sum m  *sin2wt,  C  = sum m  *cos2wt   (tau sums, mask^1 like ref)
//   S2 = sum m^2*sin2wt,  C2 = sum m^2*cos2wt   (denominators use mask^2)
//   Sy = sum y*m*sin wt,  Cy = sum y*m*cos wt,  M2 = sum m^2
// with sin2wt = 2 s0 c0, cos2wt = 1 - 2 s0^2.  Epilogue (no trig!):
//   cos2phi = C/h, sin2phi = S/h, h = sqrt(S^2+C^2)  (tan2phi = S/C == ref tau)
//   cosphi = sqrt((1+cos2phi)/2), sinphi = copysign(sqrt((1-cos2phi)/2), S)
//   YC =  cosphi*Cy + sinphi*Sy          (= sum y m cos(wt - phi))
//   YS =  cosphi*Sy - sinphi*Cy          (= sum y m sin(wt - phi))
//   cross = cos2phi*C2 + sin2phi*S2
//   CC = (M2 + cross)/2, SS = (M2 - cross)/2
// identical math to the reference; differences are ~1e-6 relative while the
// reference's own fp32 radian rounding is ~4e-4 rad/sample (proved invisible
// at the bf16 compare floor in rounds 3/5).
__global__ __launch_bounds__(1024) void ls_power_kernel(
    const float* __restrict__ t,
    const float* __restrict__ y,
    const float* __restrict__ mask,
    const float* __restrict__ freqs,
    float* __restrict__ p_out)
{
    const int tid   = threadIdx.x;
    const int fi    = tid & (FPB - 1);
    const int slice = tid >> 6;               // 0..15, wave index
    const int b     = blockIdx.y;
    const int f     = blockIdx.x * FPB + fi;

    const float freq = freqs[f];

    // wave-uniform float4 chunk base into the (b)-th row
    const int c0i = __builtin_amdgcn_readfirstlane(b * (N_ / 4) + slice * NC);
    const float4* __restrict__ t4 = (const float4*)t;
    const float4* __restrict__ y4 = (const float4*)y;
    const float4* __restrict__ m4 = (const float4*)mask;

    __shared__ float red[SLICES][7][FPB];

    float S = 0.f, C = 0.f, S2 = 0.f, C2 = 0.f, Sy = 0.f, Cy = 0.f, M2 = 0.f;

#pragma unroll 4
    for (int ch = 0; ch < NC; ++ch) {
        float4 tv = t4[c0i + ch];
        float4 yv = y4[c0i + ch];
        float4 mv = m4[c0i + ch];
#pragma unroll
        for (int k = 0; k < 4; ++k) {
            float tn = (&tv.x)[k];
            float yn = (&yv.x)[k];
            float mn = (&mv.x)[k];
            float ph = freq * tn;                          // revolutions, hi
            float pe = __builtin_fmaf(freq, tn, -ph);      // exact residual
            float r  = __builtin_amdgcn_fractf(ph) + pe;   // ~1ulp frac rev
            float s0 = __builtin_amdgcn_sinf(r);           // sin(wt)
            float cc0 = __builtin_amdgcn_cosf(r);          // cos(wt)
            float t1 = s0 * cc0;
            float s2 = t1 + t1;                            // sin(2wt)
            float u  = s0 + s0;
            float c2 = __builtin_fmaf(-u, s0, 1.0f);       // cos(2wt) = 1-2s0^2
            float m2 = mn * mn;
            float ym = yn * mn;
            S  = __builtin_fmaf(s2, mn, S);
            C  = __builtin_fmaf(c2, mn, C);
            S2 = __builtin_fmaf(s2, m2, S2);
            C2 = __builtin_fmaf(c2, m2, C2);
            Sy = __builtin_fmaf(s0, ym, Sy);
            Cy = __builtin_fmaf(cc0, ym, Cy);
            M2 += m2;
        }
    }

    red[slice][0][fi] = S;
    red[slice][1][fi] = C;
    red[slice][2][fi] = S2;
    red[slice][3][fi] = C2;
    red[slice][4][fi] = Sy;
    red[slice][5][fi] = Cy;
    red[slice][6][fi] = M2;
    __syncthreads();

    if (slice == 0) {
        float rS = 0.f, rC = 0.f, rS2 = 0.f, rC2 = 0.f, rSy = 0.f, rCy = 0.f, rM2 = 0.f;
#pragma unroll
        for (int k = 0; k < SLICES; ++k) {
            rS  += red[k][0][fi];
            rC  += red[k][1][fi];
            rS2 += red[k][2][fi];
            rC2 += red[k][3][fi];
            rSy += red[k][4][fi];
            rCy += red[k][5][fi];
            rM2 += red[k][6][fi];
        }

        float h      = sqrtf(__builtin_fmaf(rS, rS, rC * rC)) + 1e-30f;
        float cos2p  = rC / h;
        float sin2p  = rS / h;
        float cosp   = sqrtf(0.5f * (1.0f + cos2p));
        float sinp   = __builtin_copysignf(sqrtf(0.5f * (1.0f - cos2p)), rS);

        float YC = cosp * rCy + sinp * rSy;
        float YS = cosp * rSy - sinp * rCy;
        float cross = cos2p * rC2 + sin2p * rS2;
        float CCd = 0.5f * (rM2 + cross);
        float SSd = 0.5f * (rM2 - cross);

        float p_cos = (YC * YC) / (CCd + 1e-10f);
        float p_sin = (YS * YS) / (SSd + 1e-10f);
        float p = 0.5f * (p_cos + p_sin);

        // fap = 1 - (1 - exp(-p))^2048 -- keep the naive fp32 path (matches np)
        float fap = 1.0f - powf(1.0f - expf(-p), 2048.0f);
        p = p * (1.0f / (fap + 1e-5f));

        p_out[b * F_ + f] = p;
    }
}

// One block per batch: trapezoid integral over F, then in-place normalize.
__global__ __launch_bounds__(256) void ls_norm_kernel(
    const float* __restrict__ freqs,
    float* __restrict__ p)   // d_out, in place
{
    const int b   = blockIdx.x;
    const int tid = threadIdx.x;
    float* __restrict__ pb = p + b * F_;

    float local = 0.0f;
    for (int j = tid; j < F_ - 1; j += 256) {
        float df = freqs[j + 1] - freqs[j];
        local += 0.5f * (pb[j] + pb[j + 1]) * df;
    }

    __shared__ float sred[256];
    sred[tid] = local;
    __syncthreads();
    for (int o = 128; o > 0; o >>= 1) {
        if (tid < o) sred[tid] += sred[tid + o];
        __syncthreads();
    }
    const float integral = sred[0] + 1e-10f;

#pragma unroll
    for (int k = 0; k < F_ / 256; ++k) {
        int j = tid + k * 256;
        pb[j] = pb[j] / integral;
    }
}

extern "C" void kernel_launch(void* const* d_in, const int* in_sizes, int n_in,
                              void* d_out, int out_size, void* d_ws, size_t ws_size,
                              hipStream_t stream) {
    const float* t     = (const float*)d_in[0];
    const float* y     = (const float*)d_in[1];
    const float* mask  = (const float*)d_in[2];
    const float* freqs = (const float*)d_in[3];
    float* out = (float*)d_out;

    dim3 grid1(F_ / FPB, B_);   // 32 x 16 = 512 blocks x 1024 threads
    ls_power_kernel<<<grid1, 1024, 0, stream>>>(t, y, mask, freqs, out);
    ls_norm_kernel<<<B_, 256, 0, stream>>>(freqs, out);
}

// Round 8
// 79.278 us; speedup vs baseline: 1.9029x; 1.0403x over previous
//
#include <hip/hip_runtime.h>
#include <math.h>

#define B_ 16
#define N_ 1024
#define F_ 2048
#define FPB 64            // freqs per block == lanes per wave
#define SLICES 16         // one N-slice per wave; 1024-thread blocks
#define NS (N_ / SLICES)  // 64 samples per slice
#define NC (NS / 4)       // 16 float4 chunks per slice

typedef float v2f __attribute__((ext_vector_type(2)));

// Single-pass Lomb-Scargle (Press & Rybicki), packed-FP32 inner loop.
// Two samples per VOP3P instruction (v_pk_fma_f32 etc., CDNA2+): per pair
// 16 pk-ops + 2 v_fract + 4 trans = 22 issue slots for 2 samples (vs 38
// scalar). All t/y/mask reads are wave-uniform -> s_load_dwordx4 (SGPR,
// free of VALU slots). __launch_bounds__(1024,8) caps VGPR at 64 so both
// blocks/CU are resident (32 waves/CU).
//
// Math identical to rounds 5/6 (absmax 0.0117 vs 3.1 threshold):
//   s0=sin(wt), c0=cos(wt) once per sample (hardware trig in revolutions,
//   Dekker split for ~1ulp fractional revolution);
//   sin2wt = 2 s0 c0, cos2wt = 1-2 s0^2;
//   S,C (mask^1) feed tau; S2,C2,M2 (mask^2) feed denominators;
//   epilogue uses half-angle rotation -- no trig at all.
__global__ __launch_bounds__(1024, 8) void ls_power_kernel(
    const float* __restrict__ t,
    const float* __restrict__ y,
    const float* __restrict__ mask,
    const float* __restrict__ freqs,
    float* __restrict__ p_out)
{
    const int tid   = threadIdx.x;
    const int fi    = tid & (FPB - 1);
    const int slice = tid >> 6;               // 0..15, wave index
    const int b     = blockIdx.y;
    const int f     = blockIdx.x * FPB + fi;

    const float freq = freqs[f];
    const v2f  fq2  = {freq, freq};
    const v2f  onev = {1.0f, 1.0f};
    const v2f  ntwo = {-2.0f, -2.0f};

    // wave-uniform float4 chunk base into the (b)-th row
    const int c0i = __builtin_amdgcn_readfirstlane(b * (N_ / 4) + slice * NC);
    const float4* __restrict__ t4 = (const float4*)t;
    const float4* __restrict__ y4 = (const float4*)y;
    const float4* __restrict__ m4 = (const float4*)mask;

    __shared__ float red[SLICES][7][FPB];

    v2f S = {0.f, 0.f}, C = S, S2 = S, C2 = S, Sy = S, Cy = S, M2 = S;

    auto pair = [&](float ta, float tb, float ya, float yb, float ma, float mb) {
        v2f tn = {ta, tb}, yn = {ya, yb}, mn = {ma, mb};
        v2f ph = fq2 * tn;                                  // pk_mul (revolutions)
        v2f pe = __builtin_elementwise_fma(fq2, tn, -ph);   // pk_fma, exact resid
        v2f fr = {__builtin_amdgcn_fractf(ph.x),
                  __builtin_amdgcn_fractf(ph.y)};
        v2f r  = fr + pe;                                   // pk_add
        v2f s0 = {__builtin_amdgcn_sinf(r.x), __builtin_amdgcn_sinf(r.y)};
        v2f c0 = {__builtin_amdgcn_cosf(r.x), __builtin_amdgcn_cosf(r.y)};
        v2f t1 = s0 * c0;
        v2f s2v = t1 + t1;                                  // sin(2wt)
        v2f w  = s0 * s0;
        v2f c2v = __builtin_elementwise_fma(w, ntwo, onev); // cos(2wt)
        v2f m2v = mn * mn;
        v2f ymv = yn * mn;
        S  = __builtin_elementwise_fma(s2v, mn,  S);
        C  = __builtin_elementwise_fma(c2v, mn,  C);
        S2 = __builtin_elementwise_fma(s2v, m2v, S2);
        C2 = __builtin_elementwise_fma(c2v, m2v, C2);
        Sy = __builtin_elementwise_fma(s0,  ymv, Sy);
        Cy = __builtin_elementwise_fma(c0,  ymv, Cy);
        M2 = M2 + m2v;
    };

#pragma unroll 2
    for (int ch = 0; ch < NC; ++ch) {
        float4 tv = t4[c0i + ch];
        float4 yv = y4[c0i + ch];
        float4 mv = m4[c0i + ch];
        pair(tv.x, tv.y, yv.x, yv.y, mv.x, mv.y);
        pair(tv.z, tv.w, yv.z, yv.w, mv.z, mv.w);
    }

    red[slice][0][fi] = S.x  + S.y;
    red[slice][1][fi] = C.x  + C.y;
    red[slice][2][fi] = S2.x + S2.y;
    red[slice][3][fi] = C2.x + C2.y;
    red[slice][4][fi] = Sy.x + Sy.y;
    red[slice][5][fi] = Cy.x + Cy.y;
    red[slice][6][fi] = M2.x + M2.y;
    __syncthreads();

    if (slice == 0) {
        float rS = 0.f, rC = 0.f, rS2 = 0.f, rC2 = 0.f, rSy = 0.f, rCy = 0.f, rM2 = 0.f;
#pragma unroll
        for (int k = 0; k < SLICES; ++k) {
            rS  += red[k][0][fi];
            rC  += red[k][1][fi];
            rS2 += red[k][2][fi];
            rC2 += red[k][3][fi];
            rSy += red[k][4][fi];
            rCy += red[k][5][fi];
            rM2 += red[k][6][fi];
        }

        float h      = sqrtf(__builtin_fmaf(rS, rS, rC * rC)) + 1e-30f;
        float cos2p  = rC / h;
        float sin2p  = rS / h;
        float cosp   = sqrtf(0.5f * (1.0f + cos2p));
        float sinp   = __builtin_copysignf(sqrtf(0.5f * (1.0f - cos2p)), rS);

        float YC = cosp * rCy + sinp * rSy;
        float YS = cosp * rSy - sinp * rCy;
        float cross = cos2p * rC2 + sin2p * rS2;
        float CCd = 0.5f * (rM2 + cross);
        float SSd = 0.5f * (rM2 - cross);

        float p_cos = (YC * YC) / (CCd + 1e-10f);
        float p_sin = (YS * YS) / (SSd + 1e-10f);
        float p = 0.5f * (p_cos + p_sin);

        // fap = 1 - (1 - exp(-p))^2048 -- keep the naive fp32 path (matches np)
        float fap = 1.0f - powf(1.0f - expf(-p), 2048.0f);
        p = p * (1.0f / (fap + 1e-5f));

        p_out[b * F_ + f] = p;
    }
}

// One block per batch: trapezoid integral over F, then in-place normalize.
__global__ __launch_bounds__(256) void ls_norm_kernel(
    const float* __restrict__ freqs,
    float* __restrict__ p)   // d_out, in place
{
    const int b   = blockIdx.x;
    const int tid = threadIdx.x;
    float* __restrict__ pb = p + b * F_;

    float local = 0.0f;
    for (int j = tid; j < F_ - 1; j += 256) {
        float df = freqs[j + 1] - freqs[j];
        local += 0.5f * (pb[j] + pb[j + 1]) * df;
    }

    __shared__ float sred[256];
    sred[tid] = local;
    __syncthreads();
    for (int o = 128; o > 0; o >>= 1) {
        if (tid < o) sred[tid] += sred[tid + o];
        __syncthreads();
    }
    const float integral = sred[0] + 1e-10f;

#pragma unroll
    for (int k = 0; k < F_ / 256; ++k) {
        int j = tid + k * 256;
        pb[j] = pb[j] / integral;
    }
}

extern "C" void kernel_launch(void* const* d_in, const int* in_sizes, int n_in,
                              void* d_out, int out_size, void* d_ws, size_t ws_size,
                              hipStream_t stream) {
    const float* t     = (const float*)d_in[0];
    const float* y     = (const float*)d_in[1];
    const float* mask  = (const float*)d_in[2];
    const float* freqs = (const float*)d_in[3];
    float* out = (float*)d_out;

    dim3 grid1(F_ / FPB, B_);   // 32 x 16 = 512 blocks x 1024 threads
    ls_power_kernel<<<grid1, 1024, 0, stream>>>(t, y, mask, freqs, out);
    ls_norm_kernel<<<B_, 256, 0, stream>>>(freqs, out);
}

// Round 9
// 79.036 us; speedup vs baseline: 1.9087x; 1.0031x over previous
//
#include <hip/hip_runtime.h>
#include <math.h>

#define B_ 16
#define N_ 1024
#define F_ 2048
#define FPB 64            // freqs per block == lanes per wave
#define SLICES 16         // one N-slice per wave; 1024-thread blocks
#define NS (N_ / SLICES)  // 64 samples per slice
#define NC (NS / 4)       // 16 float4 chunks per slice

typedef float v2f __attribute__((ext_vector_type(2)));

// Single-pass Lomb-Scargle (Press & Rybicki), packed-FP32 inner loop.
// ROUND 9 change (single, attributable): t/y/mask staged in LDS once per
// block; the inner loop reads them as wave-uniform ds_read_b128 broadcasts
// (same address on all 64 lanes = conflict-free) instead of VMEM loads.
// Round-8 post-mortem showed the loop runs 3.5x above its issue floor with
// ~170 cy/pair unexplained -- consistent with unhidden global-load latency,
// which LDS staging removes.
//
// Math identical to rounds 5/6/8 (absmax 0.008-0.012 vs 3.1 threshold):
//   s0=sin(wt), c0=cos(wt) once per sample (hardware trig in revolutions,
//   Dekker split for ~1ulp fractional revolution);
//   sin2wt = 2 s0 c0, cos2wt = 1-2 s0^2;
//   S,C (mask^1) feed tau; S2,C2,M2 (mask^2) feed denominators;
//   epilogue uses half-angle rotation -- no trig at all.
__global__ __launch_bounds__(1024, 8) void ls_power_kernel(
    const float* __restrict__ t,
    const float* __restrict__ y,
    const float* __restrict__ mask,
    const float* __restrict__ freqs,
    float* __restrict__ p_out)
{
    const int tid   = threadIdx.x;
    const int fi    = tid & (FPB - 1);
    const int slice = tid >> 6;               // 0..15, wave index
    const int b     = blockIdx.y;
    const int f     = blockIdx.x * FPB + fi;

    const float freq = freqs[f];
    const v2f  fq2  = {freq, freq};
    const v2f  onev = {1.0f, 1.0f};
    const v2f  ntwo = {-2.0f, -2.0f};

    // ---- stage this batch's t/y/mask into LDS (12 KB) ----
    __shared__ float4 sh[3 * (N_ / 4)];       // [0:256) t | [256:512) y | [512:768) m
    if (tid < 3 * (N_ / 4)) {
        const int a = tid >> 8;               // which array
        const int i = tid & (N_ / 4 - 1);     // float4 index within row
        const float4* __restrict__ src =
            (a == 0) ? (const float4*)t : (a == 1) ? (const float4*)y
                                                   : (const float4*)mask;
        sh[tid] = src[b * (N_ / 4) + i];
    }

    __shared__ float red[SLICES][7][FPB];
    __syncthreads();

    const float4* __restrict__ sh_t = sh;
    const float4* __restrict__ sh_y = sh + (N_ / 4);
    const float4* __restrict__ sh_m = sh + 2 * (N_ / 4);
    const int c0 = slice * NC;                // wave-uniform chunk base

    v2f S = {0.f, 0.f}, C = S, S2 = S, C2 = S, Sy = S, Cy = S, M2 = S;

    auto pair = [&](float ta, float tb, float ya, float yb, float ma, float mb) {
        v2f tn = {ta, tb}, yn = {ya, yb}, mn = {ma, mb};
        v2f ph = fq2 * tn;                                  // pk_mul (revolutions)
        v2f pe = __builtin_elementwise_fma(fq2, tn, -ph);   // pk_fma, exact resid
        v2f fr = {__builtin_amdgcn_fractf(ph.x),
                  __builtin_amdgcn_fractf(ph.y)};
        v2f r  = fr + pe;                                   // pk_add
        v2f s0 = {__builtin_amdgcn_sinf(r.x), __builtin_amdgcn_sinf(r.y)};
        v2f c0v = {__builtin_amdgcn_cosf(r.x), __builtin_amdgcn_cosf(r.y)};
        v2f t1 = s0 * c0v;
        v2f s2v = t1 + t1;                                  // sin(2wt)
        v2f w  = s0 * s0;
        v2f c2v = __builtin_elementwise_fma(w, ntwo, onev); // cos(2wt)
        v2f m2v = mn * mn;
        v2f ymv = yn * mn;
        S  = __builtin_elementwise_fma(s2v, mn,  S);
        C  = __builtin_elementwise_fma(c2v, mn,  C);
        S2 = __builtin_elementwise_fma(s2v, m2v, S2);
        C2 = __builtin_elementwise_fma(c2v, m2v, C2);
        Sy = __builtin_elementwise_fma(s0,  ymv, Sy);
        Cy = __builtin_elementwise_fma(c0v, ymv, Cy);
        M2 = M2 + m2v;
    };

#pragma unroll 2
    for (int ch = 0; ch < NC; ++ch) {
        float4 tv = sh_t[c0 + ch];
        float4 yv = sh_y[c0 + ch];
        float4 mv = sh_m[c0 + ch];
        pair(tv.x, tv.y, yv.x, yv.y, mv.x, mv.y);
        pair(tv.z, tv.w, yv.z, yv.w, mv.z, mv.w);
    }

    red[slice][0][fi] = S.x  + S.y;
    red[slice][1][fi] = C.x  + C.y;
    red[slice][2][fi] = S2.x + S2.y;
    red[slice][3][fi] = C2.x + C2.y;
    red[slice][4][fi] = Sy.x + Sy.y;
    red[slice][5][fi] = Cy.x + Cy.y;
    red[slice][6][fi] = M2.x + M2.y;
    __syncthreads();

    if (slice == 0) {
        float rS = 0.f, rC = 0.f, rS2 = 0.f, rC2 = 0.f, rSy = 0.f, rCy = 0.f, rM2 = 0.f;
#pragma unroll
        for (int k = 0; k < SLICES; ++k) {
            rS  += red[k][0][fi];
            rC  += red[k][1][fi];
            rS2 += red[k][2][fi];
            rC2 += red[k][3][fi];
            rSy += red[k][4][fi];
            rCy += red[k][5][fi];
            rM2 += red[k][6][fi];
        }

        float h      = sqrtf(__builtin_fmaf(rS, rS, rC * rC)) + 1e-30f;
        float cos2p  = rC / h;
        float sin2p  = rS / h;
        float cosp   = sqrtf(0.5f * (1.0f + cos2p));
        float sinp   = __builtin_copysignf(sqrtf(0.5f * (1.0f - cos2p)), rS);

        float YC = cosp * rCy + sinp * rSy;
        float YS = cosp * rSy - sinp * rCy;
        float cross = cos2p * rC2 + sin2p * rS2;
        float CCd = 0.5f * (rM2 + cross);
        float SSd = 0.5f * (rM2 - cross);

        float p_cos = (YC * YC) / (CCd + 1e-10f);
        float p_sin = (YS * YS) / (SSd + 1e-10f);
        float p = 0.5f * (p_cos + p_sin);

        // fap = 1 - (1 - exp(-p))^2048 -- keep the naive fp32 path (matches np)
        float fap = 1.0f - powf(1.0f - expf(-p), 2048.0f);
        p = p * (1.0f / (fap + 1e-5f));

        p_out[b * F_ + f] = p;
    }
}

// One block per batch: trapezoid integral over F, then in-place normalize.
__global__ __launch_bounds__(256) void ls_norm_kernel(
    const float* __restrict__ freqs,
    float* __restrict__ p)   // d_out, in place
{
    const int b   = blockIdx.x;
    const int tid = threadIdx.x;
    float* __restrict__ pb = p + b * F_;

    float local = 0.0f;
    for (int j = tid; j < F_ - 1; j += 256) {
        float df = freqs[j + 1] - freqs[j];
        local += 0.5f * (pb[j] + pb[j + 1]) * df;
    }

    __shared__ float sred[256];
    sred[tid] = local;
    __syncthreads();
    for (int o = 128; o > 0; o >>= 1) {
        if (tid < o) sred[tid] += sred[tid + o];
        __syncthreads();
    }
    const float integral = sred[0] + 1e-10f;

#pragma unroll
    for (int k = 0; k < F_ / 256; ++k) {
        int j = tid + k * 256;
        pb[j] = pb[j] / integral;
    }
}

extern "C" void kernel_launch(void* const* d_in, const int* in_sizes, int n_in,
                              void* d_out, int out_size, void* d_ws, size_t ws_size,
                              hipStream_t stream) {
    const float* t     = (const float*)d_in[0];
    const float* y     = (const float*)d_in[1];
    const float* mask  = (const float*)d_in[2];
    const float* freqs = (const float*)d_in[3];
    float* out = (float*)d_out;

    dim3 grid1(F_ / FPB, B_);   // 32 x 16 = 512 blocks x 1024 threads
    ls_power_kernel<<<grid1, 1024, 0, stream>>>(t, y, mask, freqs, out);
    ls_norm_kernel<<<B_, 256, 0, stream>>>(freqs, out);
}